// Round 20
// baseline (313.946 us; speedup 1.0000x reference)
//
#include <hip/hip_runtime.h>
#include <hip/hip_bf16.h>

#define M_ROWS 16384
#define D_DIM  1024
#define K_CB   4096

#define ZTILE  128               // z rows per block
#define CTILE  256               // cb entries per chunk
#define NS     8
#define COLS_PER_SPLIT (K_CB / NS)   // 512
#define BODIES 32                    // 2 chunks x 16 (K=1024 / 64 per body)
#define MBLOCKS (M_ROWS / ZTILE)     // 128
#define SLOT_B 24576                 // ring slot bytes: Z 8KB + C 16KB

typedef __attribute__((ext_vector_type(4))) int  int4v;
typedef __attribute__((ext_vector_type(8))) int  int8v;
typedef __attribute__((ext_vector_type(16))) float f32x16;

static __device__ __forceinline__ unsigned f2sortable(float f) {
  unsigned u = __float_as_uint(f);
  return (u & 0x80000000u) ? ~u : (u | 0x80000000u);
}

static __device__ __forceinline__ float sortable2f(unsigned s) {
  unsigned u = (s & 0x80000000u) ? (s ^ 0x80000000u) : ~s;
  return __uint_as_float(u);
}

// OCP e4m3fn encode, RNE, satfinite.
static __device__ __forceinline__ unsigned char f2e4m3(float f) {
  float a = fabsf(f);
  const unsigned s = (__float_as_uint(f) >> 24) & 0x80u;
  if (a < 0.015625f) {                       // subnormal range (< 2^-6)
    int m = (int)(a * 512.0f + 0.5f);        // round(a / 2^-9)
    if (m >= 8) return (unsigned char)(s | 0x08u);   // -> 2^-6 normal
    return (unsigned char)(s | (unsigned)m);
  }
  if (a > 448.0f) a = 448.0f;
  unsigned t = __float_as_uint(a);
  t += 0x7FFFFu + ((t >> 20) & 1u);          // RNE to 3 mantissa bits
  int e = (int)(t >> 23) - 127;
  unsigned m = (t >> 20) & 7u;
  if (e > 8 || (e == 8 && m == 7u)) { e = 8; m = 6u; }   // clamp to 448
  return (unsigned char)(s | ((unsigned)(e + 7) << 3) | m);
}

static __device__ __forceinline__ void gload_lds16(const unsigned char* g, unsigned char* l) {
  __builtin_amdgcn_global_load_lds(
      (const __attribute__((address_space(1))) void*)g,
      (__attribute__((address_space(3))) void*)l, 16, 0, 0);
}

// ---------------- Kernel 1: l2-normalize rows -> fp8 e4m3 (x16, row-major) ----------------
// Output scaled by 16 (e4m3 sweet range); both operands scaled the same way
// -> dot x256, top-k order preserved; k3 rescales (SCALE = 10/256).
__global__ __launch_bounds__(256)
void k_normalize(const float* __restrict__ z, const float* __restrict__ cb,
                 unsigned char* __restrict__ zf8, unsigned char* __restrict__ cbf8) {
  const int bid = blockIdx.x;
  const float* src;
  unsigned char* dst;
  if (bid < M_ROWS) {
    src = z + (size_t)bid * D_DIM;
    dst = zf8 + (size_t)bid * D_DIM;
  } else {
    const int r = bid - M_ROWS;
    src = cb + (size_t)r * D_DIM;
    dst = cbf8 + (size_t)r * D_DIM;
  }
  const int t = threadIdx.x;
  const float4 v = ((const float4*)src)[t];
  float ss = v.x * v.x + v.y * v.y + v.z * v.z + v.w * v.w;
#pragma unroll
  for (int off = 32; off > 0; off >>= 1) ss += __shfl_down(ss, off, 64);
  __shared__ float sp[4];
  if ((t & 63) == 0) sp[t >> 6] = ss;
  __syncthreads();
  const float tot = sp[0] + sp[1] + sp[2] + sp[3];
  const float sc = 16.0f / sqrtf(tot + 1e-12f);     // l2norm * 16
  uchar4 o;
  o.x = f2e4m3(v.x * sc);
  o.y = f2e4m3(v.y * sc);
  o.z = f2e4m3(v.z * sc);
  o.w = f2e4m3(v.w * sc);
  *(uchar4*)(dst + 4 * t) = o;
}

// ---------------- Kernel 2: z128 x cb256, MX-scaled fp8 32x32x64, 3-slot ring ----------------
// R19 base with ONE structural change: the per-body __syncthreads (vmcnt(0)
// drain -- exposes z's L3 latency every body) is replaced by a 3-slot LDS
// ring with counted vmcnt(6): stage body b+2 each iter; checkpoint forces
// only body b+1's 6 loads (oldest), leaving b+2's in flight -> ~2 bodies
// (~2000+ cy) of latency cover >= L3 (~900 cy). Ring hazard: stage@b targets
// slot (b+2)%3, last read at body b-1, one barrier earlier. Stage base wraps
// on its OWN cycle (R11 bug class). LDS 72 KB dynamic -> 2 blocks/CU.
__global__ __launch_bounds__(256, 2)
void k_gemm_topk(const unsigned char* __restrict__ zf8,
                 const unsigned char* __restrict__ cbf8,
                 unsigned* __restrict__ part) {
  extern __shared__ __align__(16) unsigned char smem[];  // 73728 B = 3 x (Z 8KB | C 16KB)

  const int tid  = threadIdx.x;
  const int lane = tid & 63;
  const int wid  = tid >> 6;
  const int wc   = wid & 1;    // cb 128-block
  const int wz   = wid >> 1;   // z 64-block
  const int l31  = lane & 31;
  const int l5   = lane >> 5;

  const int wgid  = (int)blockIdx.x;
  const int split = wgid & 7;          // xcd-resident codebook slab
  const int mtile = wgid >> 3;
  const int rbase = mtile * ZTILE;
  const int cbase = split * COLS_PER_SPLIT;

  // fragment byte bases within a slot: sigma0 = (2*l5) ^ rho(r); pair at ^16
  int cA[4], zA[2];
#pragma unroll
  for (int mi = 0; mi < 4; ++mi) {
    const int r = wc * 128 + mi * 32 + l31;
    cA[mi] = 8192 + r * 64 + (((2 * l5) ^ ((r >> 1) & 3)) << 4);   // C region @ +8KB
  }
#pragma unroll
  for (int nj = 0; nj < 2; ++nj) {
    const int r = wz * 64 + nj * 32 + l31;
    zA[nj] = r * 64 + (((2 * l5) ^ ((r >> 1) & 3)) << 4);
  }

  // staging: thread -> row t>>2, 16B slot t&3; source pre-swizzled (slot ^ rho(row)).
  const long stoff = (long)(tid >> 2) * D_DIM + (((tid & 3) ^ ((tid >> 3) & 3)) << 4);
  const unsigned char* zsp = zf8 + (size_t)rbase * D_DIM + stoff;
  const unsigned char* csp = cbf8 + (size_t)cbase * D_DIM + stoff;

  f32x16 acc[4][2];
#pragma unroll
  for (int mi = 0; mi < 4; ++mi)
#pragma unroll
    for (int nj = 0; nj < 2; ++nj)
#pragma unroll
      for (int r = 0; r < 16; ++r) acc[mi][nj][r] = 0.f;

  unsigned tk[2][8];                 // sorted ascending; tk[0] = min; pure u32
#pragma unroll
  for (int l = 0; l < 2; ++l)
#pragma unroll
    for (int q = 0; q < 8; ++q) tk[l][q] = 0u;

  auto STAGE_AT = [&](int dstBase) {
    unsigned char* zd = smem + dstBase + tid * 16;
    unsigned char* cd = smem + dstBase + 8192 + tid * 16;
    gload_lds16(zsp,                zd);
    gload_lds16(zsp +  64 * D_DIM,  zd + 4096);
    gload_lds16(csp,                cd);
    gload_lds16(csp +  64 * D_DIM,  cd + 4096);
    gload_lds16(csp + 128 * D_DIM,  cd + 8192);
    gload_lds16(csp + 192 * D_DIM,  cd + 12288);
  };
  auto ADV = [&](int stagedBody) {
    if (((stagedBody + 1) & 15) == 0) {
      zsp += 64 - D_DIM;                       // Z k-tiles repeat each chunk
      csp += 64 + (CTILE * D_DIM - D_DIM);     // C -> next 256-entry slab
    } else {
      zsp += 64; csp += 64;
    }
  };
  auto EPILOGUE = [&](int chunk) {
    const int cfb0 = cbase + chunk * CTILE + wc * 128 + l5 * 4;
#pragma unroll
    for (int nj = 0; nj < 2; ++nj) {
#pragma unroll
      for (int mi = 0; mi < 4; ++mi) {
#pragma unroll
        for (int r = 0; r < 16; ++r) {
          const float v = acc[mi][nj][r];
          const unsigned idx = (unsigned)(cfb0 + mi * 32 + (r & 3) + ((r >> 2) << 3));
          const unsigned key = (f2sortable(v) & ~0xFFFu) | idx;
          if (key > tk[nj][0]) {               // pure u32 gate; sorted insert
            unsigned cur = key;
#pragma unroll
            for (int q = 0; q < 7; ++q) {
              const unsigned a = tk[nj][q + 1];
              tk[nj][q] = (a < cur) ? a : cur;
              cur       = (a < cur) ? cur : a;
            }
            tk[nj][7] = cur;
          }
          acc[mi][nj][r] = 0.f;
        }
      }
    }
  };

  // prologue: stage bodies 0,1 into slots 0,1; force body 0 (oldest 6) landed
  STAGE_AT(0);          ADV(0);
  STAGE_AT(SLOT_B);     ADV(1);
  asm volatile("s_waitcnt vmcnt(6)" ::: "memory");
  __builtin_amdgcn_s_barrier();
  __builtin_amdgcn_sched_barrier(0);

  int slotBase = 0;            // read slot; cycles 0,1,2
  int sdBase   = 2 * SLOT_B;   // stage dest; its own cycle 2,0,1,... = (b+2)%3
  for (int b = 0; b < BODIES; ++b) {
    const unsigned char* S = smem + slotBase;
    int8v cf[4], zr[2];
#pragma unroll
    for (int mi = 0; mi < 4; ++mi) {
      ((int4v*)&cf[mi])[0] = *(const int4v*)(S + cA[mi]);
      ((int4v*)&cf[mi])[1] = *(const int4v*)(S + (cA[mi] ^ 16));
    }
#pragma unroll
    for (int nj = 0; nj < 2; ++nj) {
      ((int4v*)&zr[nj])[0] = *(const int4v*)(S + zA[nj]);
      ((int4v*)&zr[nj])[1] = *(const int4v*)(S + (zA[nj] ^ 16));
    }

    if (b + 2 < BODIES) {        // stage body b+2 into slot (b+2)%3
      STAGE_AT(sdBase);
      ADV(b + 2);
    }

    __builtin_amdgcn_s_setprio(1);
#pragma unroll
    for (int mi = 0; mi < 4; ++mi)
#pragma unroll
      for (int nj = 0; nj < 2; ++nj)
        acc[mi][nj] = __builtin_amdgcn_mfma_scale_f32_32x32x64_f8f6f4(
            cf[mi], zr[nj], acc[mi][nj],
            0 /*A=fp8 e4m3*/, 0 /*B=fp8 e4m3*/, 0, 0x7F, 0, 0x7F);
    __builtin_amdgcn_s_setprio(0);

    if (b == 15) EPILOGUE(0);

    // checkpoint: body b+1's loads (oldest) must land; newest (b+2) stay in
    // flight. Tail: b=30 -> only b+1=31 outstanding -> drain; b=31 -> none.
    if (b + 2 < BODIES)       asm volatile("s_waitcnt vmcnt(6)" ::: "memory");
    else if (b + 1 < BODIES)  asm volatile("s_waitcnt vmcnt(0)" ::: "memory");
    if (b + 1 < BODIES) {
      __builtin_amdgcn_s_barrier();
      __builtin_amdgcn_sched_barrier(0);
    }

    // advance ring (wave-uniform; separate wraps for read and stage bases)
    slotBase += (slotBase < 2 * SLOT_B) ? SLOT_B : -2 * SLOT_B;
    sdBase   += (sdBase   < 2 * SLOT_B) ? SLOT_B : -2 * SLOT_B;
  }
  EPILOGUE(1);

  // merge: per z row 4 contributors (wc x l5) x 8 keys -> LDS, then top-8 scan
  __syncthreads();
  unsigned* mrg = (unsigned*)smem;     // [128][33] u32 = 16.9 KB
  {
    const int slotw = (wc * 2 + l5) * 8;
#pragma unroll
    for (int nj = 0; nj < 2; ++nj) {
      const int zrow = wz * 64 + nj * 32 + l31;
#pragma unroll
      for (int q = 0; q < 8; ++q) mrg[zrow * 33 + slotw + q] = tk[nj][q];
    }
  }
  __syncthreads();
  if (tid < ZTILE) {
    const unsigned* c = mrg + tid * 33;
    unsigned top[8];
#pragma unroll
    for (int p = 0; p < 8; ++p) top[p] = 0u;
    unsigned tmin = 0u;
    for (int q0 = 0; q0 < 32; ++q0) {
      const unsigned k = c[(q0 + tid) & 31];   // rotate to spread banks
      if (k > tmin) {
        int ms = 0;
        unsigned mv = top[0];
#pragma unroll
        for (int q = 1; q < 8; ++q) { if (top[q] < mv) { mv = top[q]; ms = q; } }
#pragma unroll
        for (int q = 0; q < 8; ++q) top[q] = (q == ms) ? k : top[q];
        mv = top[0];
#pragma unroll
        for (int q = 1; q < 8; ++q) mv = (top[q] < mv) ? top[q] : mv;
        tmin = mv;
      }
    }
    unsigned* dst = part + ((size_t)(rbase + tid) * NS + split) * 8;
#pragma unroll
    for (int p = 0; p < 8; ++p) dst[p] = top[p];
  }
}

// ---------------- Kernel 3: merge splits, softmax, gather E, gate ----------------
// logits computed on x16-scaled operands -> raw dot = 256x; softmax input is
// TAU * dot / 256.
template<int NSP>
__global__ __launch_bounds__(256)
void k_gate(const unsigned* __restrict__ part, const float* __restrict__ target,
            const float* __restrict__ E, float* __restrict__ out) {
  constexpr int NK = NSP * 8;
  const int row = blockIdx.x;
  const int t = threadIdx.x;
  __shared__ float s_alpha[8];
  __shared__ int s_idx[8];
  __shared__ unsigned s_key[8];

  if (t < NK) {
    unsigned k = part[(size_t)row * NK + t];
#pragma unroll
    for (int p = 0; p < 8; ++p) {
      unsigned m = k;
#pragma unroll
      for (int off = NK / 2; off > 0; off >>= 1) {
        const unsigned o = __shfl_xor(m, off, NK);
        m = (m > o) ? m : o;
      }
      if (k == m) { s_key[p] = k; k = 0u; }  // keys distinct (idx in low bits)
    }
  }
  __syncthreads();
  if (t < 8) {
    const float SCALE = 10.0f / 256.0f;
    const unsigned key = s_key[t];
    const float val  = SCALE * sortable2f(key & ~0xFFFu);
    const float vmax = SCALE * sortable2f(s_key[0] & ~0xFFFu);
    const float e = expf(val - vmax);
    float s = e;
#pragma unroll
    for (int off = 4; off > 0; off >>= 1) s += __shfl_xor(s, off, 8);
    s_alpha[t] = e / s;
    s_idx[t] = (int)(key & 0xFFFu);
  }
  __syncthreads();

  float4 g = {0.f, 0.f, 0.f, 0.f};
#pragma unroll
  for (int p = 0; p < 8; ++p) {
    const float a = s_alpha[p];
    const float4 e4 = ((const float4*)E)[(size_t)s_idx[p] * 256 + t];
    g.x += a * e4.x;
    g.y += a * e4.y;
    g.z += a * e4.z;
    g.w += a * e4.w;
  }
  const float4 tg = ((const float4*)target)[(size_t)row * 256 + t];
  float4 o;
  o.x = tg.x * (1.f + g.x);
  o.y = tg.y * (1.f + g.y);
  o.z = tg.z * (1.f + g.z);
  o.w = tg.w * (1.f + g.w);
  ((float4*)out)[(size_t)row * 256 + t] = o;
}

extern "C" void kernel_launch(void* const* d_in, const int* in_sizes, int n_in,
                              void* d_out, int out_size, void* d_ws, size_t ws_size,
                              hipStream_t stream) {
  const float* z      = (const float*)d_in[0];
  const float* target = (const float*)d_in[1];
  const float* cb     = (const float*)d_in[2];
  const float* E      = (const float*)d_in[3];
  float* out = (float*)d_out;

  // d_out doubles as scratch for the fp8 normalized matrices (dead before k_gate writes)
  unsigned char* zf8  = (unsigned char*)d_out;                        // 16 MB
  unsigned char* cbf8 = (unsigned char*)d_out + 16777216;             // 4 MB @ +16MB
  unsigned* part = (unsigned*)d_ws;                                   // 4 MB

  hipFuncSetAttribute((const void*)k_gemm_topk,
                      hipFuncAttributeMaxDynamicSharedMemorySize, 73728);

  k_normalize<<<dim3(M_ROWS + K_CB), dim3(256), 0, stream>>>(z, cb, zf8, cbf8);
  k_gemm_topk<<<dim3(MBLOCKS * NS), dim3(256), 73728, stream>>>(zf8, cbf8, part);
  k_gate<NS><<<dim3(M_ROWS), dim3(256), 0, stream>>>(part, target, E, out);
}

// Round 21
// 220.150 us; speedup vs baseline: 1.4261x; 1.4261x over previous
//
#include <hip/hip_runtime.h>
#include <hip/hip_bf16.h>

#define M_ROWS 16384
#define D_DIM  1024
#define K_CB   4096

#define ZTILE  128               // z rows per block
#define CTILE  128               // cb entries per chunk
#define NS     8
#define COLS_PER_SPLIT (K_CB / NS)   // 512
#define BODIES 64                    // 4 chunks x 16 (K=1024 / 64 per body)
#define MBLOCKS (M_ROWS / ZTILE)     // 128

typedef __attribute__((ext_vector_type(4))) int  int4v;
typedef __attribute__((ext_vector_type(8))) int  int8v;
typedef __attribute__((ext_vector_type(16))) float f32x16;

static __device__ __forceinline__ unsigned f2sortable(float f) {
  unsigned u = __float_as_uint(f);
  return (u & 0x80000000u) ? ~u : (u | 0x80000000u);
}

static __device__ __forceinline__ float sortable2f(unsigned s) {
  unsigned u = (s & 0x80000000u) ? (s ^ 0x80000000u) : ~s;
  return __uint_as_float(u);
}

// OCP e4m3fn encode, RNE, satfinite.
static __device__ __forceinline__ unsigned char f2e4m3(float f) {
  float a = fabsf(f);
  const unsigned s = (__float_as_uint(f) >> 24) & 0x80u;
  if (a < 0.015625f) {                       // subnormal range (< 2^-6)
    int m = (int)(a * 512.0f + 0.5f);        // round(a / 2^-9)
    if (m >= 8) return (unsigned char)(s | 0x08u);   // -> 2^-6 normal
    return (unsigned char)(s | (unsigned)m);
  }
  if (a > 448.0f) a = 448.0f;
  unsigned t = __float_as_uint(a);
  t += 0x7FFFFu + ((t >> 20) & 1u);          // RNE to 3 mantissa bits
  int e = (int)(t >> 23) - 127;
  unsigned m = (t >> 20) & 7u;
  if (e > 8 || (e == 8 && m == 7u)) { e = 8; m = 6u; }   // clamp to 448
  return (unsigned char)(s | ((unsigned)(e + 7) << 3) | m);
}

static __device__ __forceinline__ void gload_lds16(const unsigned char* g, unsigned char* l) {
  __builtin_amdgcn_global_load_lds(
      (const __attribute__((address_space(1))) void*)g,
      (__attribute__((address_space(3))) void*)l, 16, 0, 0);
}

// ---------------- Kernel 1: l2-normalize rows -> fp8 e4m3 (x16, row-major) ----------------
// Output scaled by 16 (e4m3 sweet range); both operands scaled the same way
// -> dot x256, top-k order preserved; k3 rescales (SCALE = 10/256).
__global__ __launch_bounds__(256)
void k_normalize(const float* __restrict__ z, const float* __restrict__ cb,
                 unsigned char* __restrict__ zf8, unsigned char* __restrict__ cbf8) {
  const int bid = blockIdx.x;
  const float* src;
  unsigned char* dst;
  if (bid < M_ROWS) {
    src = z + (size_t)bid * D_DIM;
    dst = zf8 + (size_t)bid * D_DIM;
  } else {
    const int r = bid - M_ROWS;
    src = cb + (size_t)r * D_DIM;
    dst = cbf8 + (size_t)r * D_DIM;
  }
  const int t = threadIdx.x;
  const float4 v = ((const float4*)src)[t];
  float ss = v.x * v.x + v.y * v.y + v.z * v.z + v.w * v.w;
#pragma unroll
  for (int off = 32; off > 0; off >>= 1) ss += __shfl_down(ss, off, 64);
  __shared__ float sp[4];
  if ((t & 63) == 0) sp[t >> 6] = ss;
  __syncthreads();
  const float tot = sp[0] + sp[1] + sp[2] + sp[3];
  const float sc = 16.0f / sqrtf(tot + 1e-12f);     // l2norm * 16
  uchar4 o;
  o.x = f2e4m3(v.x * sc);
  o.y = f2e4m3(v.y * sc);
  o.z = f2e4m3(v.z * sc);
  o.w = f2e4m3(v.w * sc);
  *(uchar4*)(dst + 4 * t) = o;
}

// ---------------- Kernel 2: z128 x cb128 tile, MX-scaled fp8 32x32x64, dbuf ----------------
// R19 base (fastest passing: plain __syncthreads dbuf -- every manual-sync
// variant R5/R6/R12/R20 lost to it) with ONE change: tile cb 256->128 so
// acc[2][2] = 64 AGPR -> per-wave state ~124 regs -> __launch_bounds__(256,3)
// = 3 blocks/CU = 12 waves/CU (~37% occupancy, the R8/R9 sweet spot) vs
// R19's 2 blocks/20%. Three co-resident blocks with uncorrelated barriers
// keep the MFMA pipe fed during any one block's stage window. Work, traffic,
// and candidate streams invariant (CHUNKS 2->4, BODIES 32->64).
__global__ __launch_bounds__(256, 3)
void k_gemm_topk(const unsigned char* __restrict__ zf8,
                 const unsigned char* __restrict__ cbf8,
                 unsigned* __restrict__ part) {
  __shared__ __align__(16) unsigned char smem[32768];  // Z0|Z1|C0|C1 8KB each

  const int tid  = threadIdx.x;
  const int lane = tid & 63;
  const int wid  = tid >> 6;
  const int wc   = wid & 1;    // cb 64-block
  const int wz   = wid >> 1;   // z 64-block
  const int l31  = lane & 31;
  const int l5   = lane >> 5;

  const int wgid  = (int)blockIdx.x;
  const int split = wgid & 7;          // xcd-resident codebook slab
  const int mtile = wgid >> 3;
  const int rbase = mtile * ZTILE;
  const int cbase = split * COLS_PER_SPLIT;

  // fragment byte bases: sigma0 = (2*l5) ^ rho(r); second b128 at base ^ 16
  int cA[2], zA[2];
#pragma unroll
  for (int mi = 0; mi < 2; ++mi) {
    const int r = wc * 64 + mi * 32 + l31;
    cA[mi] = r * 64 + (((2 * l5) ^ ((r >> 1) & 3)) << 4);
  }
#pragma unroll
  for (int nj = 0; nj < 2; ++nj) {
    const int r = wz * 64 + nj * 32 + l31;
    zA[nj] = r * 64 + (((2 * l5) ^ ((r >> 1) & 3)) << 4);
  }

  // staging: thread -> row t>>2, 16B slot t&3; source pre-swizzled (slot ^ rho(row)).
  const long stoff = (long)(tid >> 2) * D_DIM + (((tid & 3) ^ ((tid >> 3) & 3)) << 4);
  const unsigned char* zsp = zf8 + (size_t)rbase * D_DIM + stoff;
  const unsigned char* csp = cbf8 + (size_t)cbase * D_DIM + stoff;

  f32x16 acc[2][2];
#pragma unroll
  for (int mi = 0; mi < 2; ++mi)
#pragma unroll
    for (int nj = 0; nj < 2; ++nj)
#pragma unroll
      for (int r = 0; r < 16; ++r) acc[mi][nj][r] = 0.f;

  unsigned tk[2][8];                 // sorted ascending; tk[0] = min; pure u32
#pragma unroll
  for (int l = 0; l < 2; ++l)
#pragma unroll
    for (int q = 0; q < 8; ++q) tk[l][q] = 0u;

  auto STAGE = [&](int par) {
    unsigned char* zd = smem + par * 8192 + tid * 16;
    unsigned char* cd = smem + 16384 + par * 8192 + tid * 16;
    gload_lds16(zsp,               zd);
    gload_lds16(zsp + 64 * D_DIM,  zd + 4096);
    gload_lds16(csp,               cd);
    gload_lds16(csp + 64 * D_DIM,  cd + 4096);
  };
  auto ADV = [&](int stagedBody) {
    if (((stagedBody + 1) & 15) == 0) {
      zsp += 64 - D_DIM;                       // Z k-tiles repeat each chunk
      csp += 64 + (CTILE * D_DIM - D_DIM);     // C -> next 128-entry slab
    } else {
      zsp += 64; csp += 64;
    }
  };
  auto COMPUTE = [&](int par) {
    const unsigned char* Z = smem + par * 8192;
    const unsigned char* C = smem + 16384 + par * 8192;
    int8v cf[2], zr[2];
#pragma unroll
    for (int mi = 0; mi < 2; ++mi) {
      ((int4v*)&cf[mi])[0] = *(const int4v*)(C + cA[mi]);
      ((int4v*)&cf[mi])[1] = *(const int4v*)(C + (cA[mi] ^ 16));
    }
#pragma unroll
    for (int nj = 0; nj < 2; ++nj) {
      ((int4v*)&zr[nj])[0] = *(const int4v*)(Z + zA[nj]);
      ((int4v*)&zr[nj])[1] = *(const int4v*)(Z + (zA[nj] ^ 16));
    }
    __builtin_amdgcn_s_setprio(1);
#pragma unroll
    for (int mi = 0; mi < 2; ++mi)
#pragma unroll
      for (int nj = 0; nj < 2; ++nj)
        acc[mi][nj] = __builtin_amdgcn_mfma_scale_f32_32x32x64_f8f6f4(
            cf[mi], zr[nj], acc[mi][nj],
            0 /*A=fp8 e4m3*/, 0 /*B=fp8 e4m3*/, 0, 0x7F, 0, 0x7F);
    __builtin_amdgcn_s_setprio(0);
  };
  auto EPILOGUE = [&](int chunk) {
    const int cfb0 = cbase + chunk * CTILE + wc * 64 + l5 * 4;
#pragma unroll
    for (int nj = 0; nj < 2; ++nj) {
#pragma unroll
      for (int mi = 0; mi < 2; ++mi) {
#pragma unroll
        for (int r = 0; r < 16; ++r) {
          const float v = acc[mi][nj][r];
          const unsigned idx = (unsigned)(cfb0 + mi * 32 + (r & 3) + ((r >> 2) << 3));
          const unsigned key = (f2sortable(v) & ~0xFFFu) | idx;
          if (key > tk[nj][0]) {               // pure u32 gate; sorted insert
            unsigned cur = key;
#pragma unroll
            for (int q = 0; q < 7; ++q) {
              const unsigned a = tk[nj][q + 1];
              tk[nj][q] = (a < cur) ? a : cur;
              cur       = (a < cur) ? cur : a;
            }
            tk[nj][7] = cur;
          }
          acc[mi][nj][r] = 0.f;
        }
      }
    }
  };

  // prologue: stage body 0 -> buf0
  STAGE(0);
  ADV(0);
  __syncthreads();

  for (int b = 0; b < BODIES; b += 2) {
    STAGE(1);              // body b+1 -> buf1
    ADV(b + 1);
    COMPUTE(0);
    __syncthreads();

    if (b + 2 < BODIES) {
      STAGE(0);            // body b+2 -> buf0
      ADV(b + 2);
    }
    COMPUTE(1);
    if ((b & 15) == 14) EPILOGUE((b + 1) >> 4);   // chunks end at bodies 15/31/47/63
    __syncthreads();
  }

  // merge: per z row 4 contributors (wc x l5) x 8 keys -> LDS, then top-8 scan
  unsigned* mrg = (unsigned*)smem;     // [128][33] u32 = 16.9 KB
  {
    const int slotw = (wc * 2 + l5) * 8;
#pragma unroll
    for (int nj = 0; nj < 2; ++nj) {
      const int zrow = wz * 64 + nj * 32 + l31;
#pragma unroll
      for (int q = 0; q < 8; ++q) mrg[zrow * 33 + slotw + q] = tk[nj][q];
    }
  }
  __syncthreads();
  if (tid < ZTILE) {
    const unsigned* c = mrg + tid * 33;
    unsigned top[8];
#pragma unroll
    for (int p = 0; p < 8; ++p) top[p] = 0u;
    unsigned tmin = 0u;
    for (int q0 = 0; q0 < 32; ++q0) {
      const unsigned k = c[(q0 + tid) & 31];   // rotate to spread banks
      if (k > tmin) {
        int ms = 0;
        unsigned mv = top[0];
#pragma unroll
        for (int q = 1; q < 8; ++q) { if (top[q] < mv) { mv = top[q]; ms = q; } }
#pragma unroll
        for (int q = 0; q < 8; ++q) top[q] = (q == ms) ? k : top[q];
        mv = top[0];
#pragma unroll
        for (int q = 1; q < 8; ++q) mv = (top[q] < mv) ? top[q] : mv;
        tmin = mv;
      }
    }
    unsigned* dst = part + ((size_t)(rbase + tid) * NS + split) * 8;
#pragma unroll
    for (int p = 0; p < 8; ++p) dst[p] = top[p];
  }
}

// ---------------- Kernel 3: merge splits, softmax, gather E, gate ----------------
// logits computed on x16-scaled operands -> raw dot = 256x; softmax input is
// TAU * dot / 256.
template<int NSP>
__global__ __launch_bounds__(256)
void k_gate(const unsigned* __restrict__ part, const float* __restrict__ target,
            const float* __restrict__ E, float* __restrict__ out) {
  constexpr int NK = NSP * 8;
  const int row = blockIdx.x;
  const int t = threadIdx.x;
  __shared__ float s_alpha[8];
  __shared__ int s_idx[8];
  __shared__ unsigned s_key[8];

  if (t < NK) {
    unsigned k = part[(size_t)row * NK + t];
#pragma unroll
    for (int p = 0; p < 8; ++p) {
      unsigned m = k;
#pragma unroll
      for (int off = NK / 2; off > 0; off >>= 1) {
        const unsigned o = __shfl_xor(m, off, NK);
        m = (m > o) ? m : o;
      }
      if (k == m) { s_key[p] = k; k = 0u; }  // keys distinct (idx in low bits)
    }
  }
  __syncthreads();
  if (t < 8) {
    const float SCALE = 10.0f / 256.0f;
    const unsigned key = s_key[t];
    const float val  = SCALE * sortable2f(key & ~0xFFFu);
    const float vmax = SCALE * sortable2f(s_key[0] & ~0xFFFu);
    const float e = expf(val - vmax);
    float s = e;
#pragma unroll
    for (int off = 4; off > 0; off >>= 1) s += __shfl_xor(s, off, 8);
    s_alpha[t] = e / s;
    s_idx[t] = (int)(key & 0xFFFu);
  }
  __syncthreads();

  float4 g = {0.f, 0.f, 0.f, 0.f};
#pragma unroll
  for (int p = 0; p < 8; ++p) {
    const float a = s_alpha[p];
    const float4 e4 = ((const float4*)E)[(size_t)s_idx[p] * 256 + t];
    g.x += a * e4.x;
    g.y += a * e4.y;
    g.z += a * e4.z;
    g.w += a * e4.w;
  }
  const float4 tg = ((const float4*)target)[(size_t)row * 256 + t];
  float4 o;
  o.x = tg.x * (1.f + g.x);
  o.y = tg.y * (1.f + g.y);
  o.z = tg.z * (1.f + g.z);
  o.w = tg.w * (1.f + g.w);
  ((float4*)out)[(size_t)row * 256 + t] = o;
}

extern "C" void kernel_launch(void* const* d_in, const int* in_sizes, int n_in,
                              void* d_out, int out_size, void* d_ws, size_t ws_size,
                              hipStream_t stream) {
  const float* z      = (const float*)d_in[0];
  const float* target = (const float*)d_in[1];
  const float* cb     = (const float*)d_in[2];
  const float* E      = (const float*)d_in[3];
  float* out = (float*)d_out;

  // d_out doubles as scratch for the fp8 normalized matrices (dead before k_gate writes)
  unsigned char* zf8  = (unsigned char*)d_out;                        // 16 MB
  unsigned char* cbf8 = (unsigned char*)d_out + 16777216;             // 4 MB @ +16MB
  unsigned* part = (unsigned*)d_ws;                                   // 4 MB

  k_normalize<<<dim3(M_ROWS + K_CB), dim3(256), 0, stream>>>(z, cb, zf8, cbf8);
  k_gemm_topk<<<dim3(MBLOCKS * NS), dim3(256), 0, stream>>>(zf8, cbf8, part);
  k_gate<NS><<<dim3(M_ROWS), dim3(256), 0, stream>>>(part, target, E, out);
}

// Round 22
// 219.002 us; speedup vs baseline: 1.4335x; 1.0052x over previous
//
#include <hip/hip_runtime.h>
#include <hip/hip_bf16.h>

#define M_ROWS 16384
#define D_DIM  1024
#define K_CB   4096

#define ZTILE  128               // z rows per block
#define CTILE  128               // cb entries per chunk
#define NS     8
#define COLS_PER_SPLIT (K_CB / NS)   // 512
#define BODIES 64                    // 4 chunks x 16 (K=1024 / 64 per body)
#define MBLOCKS (M_ROWS / ZTILE)     // 128

typedef __attribute__((ext_vector_type(4))) int  int4v;
typedef __attribute__((ext_vector_type(8))) int  int8v;
typedef __attribute__((ext_vector_type(16))) float f32x16;

static __device__ __forceinline__ unsigned f2sortable(float f) {
  unsigned u = __float_as_uint(f);
  return (u & 0x80000000u) ? ~u : (u | 0x80000000u);
}

static __device__ __forceinline__ float sortable2f(unsigned s) {
  unsigned u = (s & 0x80000000u) ? (s ^ 0x80000000u) : ~s;
  return __uint_as_float(u);
}

// OCP e4m3fn encode, RNE, satfinite.
static __device__ __forceinline__ unsigned char f2e4m3(float f) {
  float a = fabsf(f);
  const unsigned s = (__float_as_uint(f) >> 24) & 0x80u;
  if (a < 0.015625f) {                       // subnormal range (< 2^-6)
    int m = (int)(a * 512.0f + 0.5f);        // round(a / 2^-9)
    if (m >= 8) return (unsigned char)(s | 0x08u);   // -> 2^-6 normal
    return (unsigned char)(s | (unsigned)m);
  }
  if (a > 448.0f) a = 448.0f;
  unsigned t = __float_as_uint(a);
  t += 0x7FFFFu + ((t >> 20) & 1u);          // RNE to 3 mantissa bits
  int e = (int)(t >> 23) - 127;
  unsigned m = (t >> 20) & 7u;
  if (e > 8 || (e == 8 && m == 7u)) { e = 8; m = 6u; }   // clamp to 448
  return (unsigned char)(s | ((unsigned)(e + 7) << 3) | m);
}

static __device__ __forceinline__ void gload_lds16(const unsigned char* g, unsigned char* l) {
  __builtin_amdgcn_global_load_lds(
      (const __attribute__((address_space(1))) void*)g,
      (__attribute__((address_space(3))) void*)l, 16, 0, 0);
}

// ---------------- Kernel 1: l2-normalize rows -> fp8 e4m3 (x16), wave-per-row ----------------
// One wave per row (4 rows / 256-thread block): no LDS, no barriers. Lane
// handles 16 elems (4 float4 at lane+64i, coalesced); wave-xor shuffle reduce.
__global__ __launch_bounds__(256)
void k_normalize(const float* __restrict__ z, const float* __restrict__ cb,
                 unsigned char* __restrict__ zf8, unsigned char* __restrict__ cbf8) {
  const int row  = blockIdx.x * 4 + (threadIdx.x >> 6);
  const int lane = threadIdx.x & 63;
  const float* src;
  unsigned char* dst;
  if (row < M_ROWS) {
    src = z + (size_t)row * D_DIM;
    dst = zf8 + (size_t)row * D_DIM;
  } else {
    const int r = row - M_ROWS;
    src = cb + (size_t)r * D_DIM;
    dst = cbf8 + (size_t)r * D_DIM;
  }
  float4 v[4];
  float ss = 0.f;
#pragma unroll
  for (int i = 0; i < 4; ++i) {
    v[i] = ((const float4*)src)[lane + 64 * i];
    ss += v[i].x * v[i].x + v[i].y * v[i].y + v[i].z * v[i].z + v[i].w * v[i].w;
  }
#pragma unroll
  for (int off = 32; off > 0; off >>= 1) ss += __shfl_xor(ss, off, 64);
  const float sc = 16.0f / sqrtf(ss + 1e-12f);     // l2norm * 16
#pragma unroll
  for (int i = 0; i < 4; ++i) {
    uchar4 o;
    o.x = f2e4m3(v[i].x * sc);
    o.y = f2e4m3(v[i].y * sc);
    o.z = f2e4m3(v[i].z * sc);
    o.w = f2e4m3(v[i].w * sc);
    ((uchar4*)dst)[lane + 64 * i] = o;
  }
}

// ---------------- Kernel 2: z128 x cb128 tile, MX-scaled fp8 32x32x64, dbuf ----------------
// R21 best-known (134 us, passing): plain __syncthreads dbuf (every manual-
// sync variant lost to it), 3 blocks/CU, acc[2][2]. UNCHANGED this round.
__global__ __launch_bounds__(256, 3)
void k_gemm_topk(const unsigned char* __restrict__ zf8,
                 const unsigned char* __restrict__ cbf8,
                 unsigned* __restrict__ part) {
  __shared__ __align__(16) unsigned char smem[32768];  // Z0|Z1|C0|C1 8KB each

  const int tid  = threadIdx.x;
  const int lane = tid & 63;
  const int wid  = tid >> 6;
  const int wc   = wid & 1;    // cb 64-block
  const int wz   = wid >> 1;   // z 64-block
  const int l31  = lane & 31;
  const int l5   = lane >> 5;

  const int wgid  = (int)blockIdx.x;
  const int split = wgid & 7;          // xcd-resident codebook slab
  const int mtile = wgid >> 3;
  const int rbase = mtile * ZTILE;
  const int cbase = split * COLS_PER_SPLIT;

  // fragment byte bases: sigma0 = (2*l5) ^ rho(r); second b128 at base ^ 16
  int cA[2], zA[2];
#pragma unroll
  for (int mi = 0; mi < 2; ++mi) {
    const int r = wc * 64 + mi * 32 + l31;
    cA[mi] = r * 64 + (((2 * l5) ^ ((r >> 1) & 3)) << 4);
  }
#pragma unroll
  for (int nj = 0; nj < 2; ++nj) {
    const int r = wz * 64 + nj * 32 + l31;
    zA[nj] = r * 64 + (((2 * l5) ^ ((r >> 1) & 3)) << 4);
  }

  // staging: thread -> row t>>2, 16B slot t&3; source pre-swizzled (slot ^ rho(row)).
  const long stoff = (long)(tid >> 2) * D_DIM + (((tid & 3) ^ ((tid >> 3) & 3)) << 4);
  const unsigned char* zsp = zf8 + (size_t)rbase * D_DIM + stoff;
  const unsigned char* csp = cbf8 + (size_t)cbase * D_DIM + stoff;

  f32x16 acc[2][2];
#pragma unroll
  for (int mi = 0; mi < 2; ++mi)
#pragma unroll
    for (int nj = 0; nj < 2; ++nj)
#pragma unroll
      for (int r = 0; r < 16; ++r) acc[mi][nj][r] = 0.f;

  unsigned tk[2][8];                 // sorted ascending; tk[0] = min; pure u32
#pragma unroll
  for (int l = 0; l < 2; ++l)
#pragma unroll
    for (int q = 0; q < 8; ++q) tk[l][q] = 0u;

  auto STAGE = [&](int par) {
    unsigned char* zd = smem + par * 8192 + tid * 16;
    unsigned char* cd = smem + 16384 + par * 8192 + tid * 16;
    gload_lds16(zsp,               zd);
    gload_lds16(zsp + 64 * D_DIM,  zd + 4096);
    gload_lds16(csp,               cd);
    gload_lds16(csp + 64 * D_DIM,  cd + 4096);
  };
  auto ADV = [&](int stagedBody) {
    if (((stagedBody + 1) & 15) == 0) {
      zsp += 64 - D_DIM;                       // Z k-tiles repeat each chunk
      csp += 64 + (CTILE * D_DIM - D_DIM);     // C -> next 128-entry slab
    } else {
      zsp += 64; csp += 64;
    }
  };
  auto COMPUTE = [&](int par) {
    const unsigned char* Z = smem + par * 8192;
    const unsigned char* C = smem + 16384 + par * 8192;
    int8v cf[2], zr[2];
#pragma unroll
    for (int mi = 0; mi < 2; ++mi) {
      ((int4v*)&cf[mi])[0] = *(const int4v*)(C + cA[mi]);
      ((int4v*)&cf[mi])[1] = *(const int4v*)(C + (cA[mi] ^ 16));
    }
#pragma unroll
    for (int nj = 0; nj < 2; ++nj) {
      ((int4v*)&zr[nj])[0] = *(const int4v*)(Z + zA[nj]);
      ((int4v*)&zr[nj])[1] = *(const int4v*)(Z + (zA[nj] ^ 16));
    }
    __builtin_amdgcn_s_setprio(1);
#pragma unroll
    for (int mi = 0; mi < 2; ++mi)
#pragma unroll
      for (int nj = 0; nj < 2; ++nj)
        acc[mi][nj] = __builtin_amdgcn_mfma_scale_f32_32x32x64_f8f6f4(
            cf[mi], zr[nj], acc[mi][nj],
            0 /*A=fp8 e4m3*/, 0 /*B=fp8 e4m3*/, 0, 0x7F, 0, 0x7F);
    __builtin_amdgcn_s_setprio(0);
  };
  auto EPILOGUE = [&](int chunk) {
    const int cfb0 = cbase + chunk * CTILE + wc * 64 + l5 * 4;
#pragma unroll
    for (int nj = 0; nj < 2; ++nj) {
#pragma unroll
      for (int mi = 0; mi < 2; ++mi) {
#pragma unroll
        for (int r = 0; r < 16; ++r) {
          const float v = acc[mi][nj][r];
          const unsigned idx = (unsigned)(cfb0 + mi * 32 + (r & 3) + ((r >> 2) << 3));
          const unsigned key = (f2sortable(v) & ~0xFFFu) | idx;
          if (key > tk[nj][0]) {               // pure u32 gate; sorted insert
            unsigned cur = key;
#pragma unroll
            for (int q = 0; q < 7; ++q) {
              const unsigned a = tk[nj][q + 1];
              tk[nj][q] = (a < cur) ? a : cur;
              cur       = (a < cur) ? cur : a;
            }
            tk[nj][7] = cur;
          }
          acc[mi][nj][r] = 0.f;
        }
      }
    }
  };

  // prologue: stage body 0 -> buf0
  STAGE(0);
  ADV(0);
  __syncthreads();

  for (int b = 0; b < BODIES; b += 2) {
    STAGE(1);              // body b+1 -> buf1
    ADV(b + 1);
    COMPUTE(0);
    __syncthreads();

    if (b + 2 < BODIES) {
      STAGE(0);            // body b+2 -> buf0
      ADV(b + 2);
    }
    COMPUTE(1);
    if ((b & 15) == 14) EPILOGUE((b + 1) >> 4);   // chunks end at bodies 15/31/47/63
    __syncthreads();
  }

  // merge: per z row 4 contributors (wc x l5) x 8 keys -> LDS, then top-8 scan
  unsigned* mrg = (unsigned*)smem;     // [128][33] u32 = 16.9 KB
  {
    const int slotw = (wc * 2 + l5) * 8;
#pragma unroll
    for (int nj = 0; nj < 2; ++nj) {
      const int zrow = wz * 64 + nj * 32 + l31;
#pragma unroll
      for (int q = 0; q < 8; ++q) mrg[zrow * 33 + slotw + q] = tk[nj][q];
    }
  }
  __syncthreads();
  if (tid < ZTILE) {
    const unsigned* c = mrg + tid * 33;
    unsigned top[8];
#pragma unroll
    for (int p = 0; p < 8; ++p) top[p] = 0u;
    unsigned tmin = 0u;
    for (int q0 = 0; q0 < 32; ++q0) {
      const unsigned k = c[(q0 + tid) & 31];   // rotate to spread banks
      if (k > tmin) {
        int ms = 0;
        unsigned mv = top[0];
#pragma unroll
        for (int q = 1; q < 8; ++q) { if (top[q] < mv) { mv = top[q]; ms = q; } }
#pragma unroll
        for (int q = 0; q < 8; ++q) top[q] = (q == ms) ? k : top[q];
        mv = top[0];
#pragma unroll
        for (int q = 1; q < 8; ++q) mv = (top[q] < mv) ? top[q] : mv;
        tmin = mv;
      }
    }
    unsigned* dst = part + ((size_t)(rbase + tid) * NS + split) * 8;
#pragma unroll
    for (int p = 0; p < 8; ++p) dst[p] = top[p];
  }
}

// ---------------- Kernel 3: wave-per-row merge + softmax + gather + gate ----------------
// One wave per row (4 rows / 256-thread block): lane l holds key l of the 64
// candidates; top-8 via 8x wave-xor-max (keys distinct by idx bits); softmax
// computed redundantly per lane (8 expf, cheap); gather/gate coalesced at
// lane+64i float4. No LDS, no barriers. SCALE = 10/256 (x16-scaled operands).
__global__ __launch_bounds__(256)
void k_gate(const unsigned* __restrict__ part, const float* __restrict__ target,
            const float* __restrict__ E, float* __restrict__ out) {
  const int row  = blockIdx.x * 4 + (threadIdx.x >> 6);
  const int lane = threadIdx.x & 63;

  unsigned k = part[(size_t)row * 64 + lane];
  unsigned kp[8];
#pragma unroll
  for (int p = 0; p < 8; ++p) {
    unsigned m = k;
#pragma unroll
    for (int off = 32; off > 0; off >>= 1) {
      const unsigned o = __shfl_xor(m, off, 64);
      m = (m > o) ? m : o;
    }
    kp[p] = m;
    if (k == m) k = 0u;
  }

  const float SCALE = 10.0f / 256.0f;
  const float vmax = SCALE * sortable2f(kp[0] & ~0xFFFu);
  float a[8];
  float s = 0.f;
#pragma unroll
  for (int p = 0; p < 8; ++p) {
    a[p] = expf(SCALE * sortable2f(kp[p] & ~0xFFFu) - vmax);
    s += a[p];
  }
  const float inv = 1.0f / s;

  float4 g[4];
#pragma unroll
  for (int i = 0; i < 4; ++i) g[i] = (float4){0.f, 0.f, 0.f, 0.f};
#pragma unroll
  for (int p = 0; p < 8; ++p) {
    const float ap = a[p] * inv;
    const float4* ep = (const float4*)(E + (size_t)(kp[p] & 0xFFFu) * D_DIM);
#pragma unroll
    for (int i = 0; i < 4; ++i) {
      const float4 e4 = ep[lane + 64 * i];
      g[i].x += ap * e4.x;
      g[i].y += ap * e4.y;
      g[i].z += ap * e4.z;
      g[i].w += ap * e4.w;
    }
  }
  const float4* tg = (const float4*)(target + (size_t)row * D_DIM);
  float4* op = (float4*)(out + (size_t)row * D_DIM);
#pragma unroll
  for (int i = 0; i < 4; ++i) {
    const float4 t4 = tg[lane + 64 * i];
    float4 o;
    o.x = t4.x * (1.f + g[i].x);
    o.y = t4.y * (1.f + g[i].y);
    o.z = t4.z * (1.f + g[i].z);
    o.w = t4.w * (1.f + g[i].w);
    op[lane + 64 * i] = o;
  }
}

extern "C" void kernel_launch(void* const* d_in, const int* in_sizes, int n_in,
                              void* d_out, int out_size, void* d_ws, size_t ws_size,
                              hipStream_t stream) {
  const float* z      = (const float*)d_in[0];
  const float* target = (const float*)d_in[1];
  const float* cb     = (const float*)d_in[2];
  const float* E      = (const float*)d_in[3];
  float* out = (float*)d_out;

  // d_out doubles as scratch for the fp8 normalized matrices (dead before k_gate writes)
  unsigned char* zf8  = (unsigned char*)d_out;                        // 16 MB
  unsigned char* cbf8 = (unsigned char*)d_out + 16777216;             // 4 MB @ +16MB
  unsigned* part = (unsigned*)d_ws;                                   // 4 MB

  k_normalize<<<dim3((M_ROWS + K_CB) / 4), dim3(256), 0, stream>>>(z, cb, zf8, cbf8);
  k_gemm_topk<<<dim3(MBLOCKS * NS), dim3(256), 0, stream>>>(zf8, cbf8, part);
  k_gate<<<dim3(M_ROWS / 4), dim3(256), 0, stream>>>(part, target, E, out);
}

// Round 23
// 186.168 us; speedup vs baseline: 1.6864x; 1.1764x over previous
//
#include <hip/hip_runtime.h>
#include <hip/hip_bf16.h>

#define M_ROWS 16384
#define D_DIM  1024
#define K_CB   4096

#define ZTILE  128               // z rows per block
#define CTILE  128               // cb entries per chunk
#define NS     8
#define COLS_PER_SPLIT (K_CB / NS)   // 512
#define BODIES 64                    // 4 chunks x 16 (K=1024 / 64 per body)
#define MBLOCKS (M_ROWS / ZTILE)     // 128

typedef __attribute__((ext_vector_type(4))) int  int4v;
typedef __attribute__((ext_vector_type(8))) int  int8v;
typedef __attribute__((ext_vector_type(8))) unsigned short ushort8;
typedef __attribute__((ext_vector_type(16))) float f32x16;

static __device__ __forceinline__ unsigned f2sortable(float f) {
  unsigned u = __float_as_uint(f);
  return (u & 0x80000000u) ? ~u : (u | 0x80000000u);
}

static __device__ __forceinline__ float sortable2f(unsigned s) {
  unsigned u = (s & 0x80000000u) ? (s ^ 0x80000000u) : ~s;
  return __uint_as_float(u);
}

static __device__ __forceinline__ unsigned short f2bf(float f) {
  unsigned u = __float_as_uint(f);
  unsigned r = ((u >> 16) & 1u) + 0x7FFFu;   // RNE
  return (unsigned short)((u + r) >> 16);
}

// OCP e4m3fn encode, RNE, satfinite.
static __device__ __forceinline__ unsigned char f2e4m3(float f) {
  float a = fabsf(f);
  const unsigned s = (__float_as_uint(f) >> 24) & 0x80u;
  if (a < 0.015625f) {                       // subnormal range (< 2^-6)
    int m = (int)(a * 512.0f + 0.5f);        // round(a / 2^-9)
    if (m >= 8) return (unsigned char)(s | 0x08u);   // -> 2^-6 normal
    return (unsigned char)(s | (unsigned)m);
  }
  if (a > 448.0f) a = 448.0f;
  unsigned t = __float_as_uint(a);
  t += 0x7FFFFu + ((t >> 20) & 1u);          // RNE to 3 mantissa bits
  int e = (int)(t >> 23) - 127;
  unsigned m = (t >> 20) & 7u;
  if (e > 8 || (e == 8 && m == 7u)) { e = 8; m = 6u; }   // clamp to 448
  return (unsigned char)(s | ((unsigned)(e + 7) << 3) | m);
}

static __device__ __forceinline__ void gload_lds16(const unsigned char* g, unsigned char* l) {
  __builtin_amdgcn_global_load_lds(
      (const __attribute__((address_space(1))) void*)g,
      (__attribute__((address_space(3))) void*)l, 16, 0, 0);
}

// ---------------- Kernel 1: l2-normalize rows -> fp8 e4m3 (x16), wave-per-row ----------------
__global__ __launch_bounds__(256)
void k_normalize(const float* __restrict__ z, const float* __restrict__ cb,
                 unsigned char* __restrict__ zf8, unsigned char* __restrict__ cbf8) {
  const int row  = blockIdx.x * 4 + (threadIdx.x >> 6);
  const int lane = threadIdx.x & 63;
  const float* src;
  unsigned char* dst;
  if (row < M_ROWS) {
    src = z + (size_t)row * D_DIM;
    dst = zf8 + (size_t)row * D_DIM;
  } else {
    const int r = row - M_ROWS;
    src = cb + (size_t)r * D_DIM;
    dst = cbf8 + (size_t)r * D_DIM;
  }
  float4 v[4];
  float ss = 0.f;
#pragma unroll
  for (int i = 0; i < 4; ++i) {
    v[i] = ((const float4*)src)[lane + 64 * i];
    ss += v[i].x * v[i].x + v[i].y * v[i].y + v[i].z * v[i].z + v[i].w * v[i].w;
  }
#pragma unroll
  for (int off = 32; off > 0; off >>= 1) ss += __shfl_xor(ss, off, 64);
  const float sc = 16.0f / sqrtf(ss + 1e-12f);     // l2norm * 16
#pragma unroll
  for (int i = 0; i < 4; ++i) {
    uchar4 o;
    o.x = f2e4m3(v[i].x * sc);
    o.y = f2e4m3(v[i].y * sc);
    o.z = f2e4m3(v[i].z * sc);
    o.w = f2e4m3(v[i].w * sc);
    ((uchar4*)dst)[lane + 64 * i] = o;
  }
}

// ---------------- Kernel 1b: E f32 -> bf16 (halves k3's gather bytes) ----------------
__global__ __launch_bounds__(256)
void k_e2bf(const float* __restrict__ E, unsigned short* __restrict__ Eb) {
  const int i = (blockIdx.x * 256 + threadIdx.x) * 8;
  const float4 a = ((const float4*)(E + i))[0];
  const float4 b = ((const float4*)(E + i))[1];
  ushort8 o;
  o[0] = f2bf(a.x); o[1] = f2bf(a.y); o[2] = f2bf(a.z); o[3] = f2bf(a.w);
  o[4] = f2bf(b.x); o[5] = f2bf(b.y); o[6] = f2bf(b.z); o[7] = f2bf(b.w);
  *(ushort8*)(Eb + i) = o;
}

// ---------------- Kernel 2: z128 x cb128 tile, MX-scaled fp8 32x32x64, dbuf ----------------
// R21/R22 best-known (134 us): plain __syncthreads dbuf, 3 blocks/CU. UNCHANGED.
__global__ __launch_bounds__(256, 3)
void k_gemm_topk(const unsigned char* __restrict__ zf8,
                 const unsigned char* __restrict__ cbf8,
                 unsigned* __restrict__ part) {
  __shared__ __align__(16) unsigned char smem[32768];  // Z0|Z1|C0|C1 8KB each

  const int tid  = threadIdx.x;
  const int lane = tid & 63;
  const int wid  = tid >> 6;
  const int wc   = wid & 1;    // cb 64-block
  const int wz   = wid >> 1;   // z 64-block
  const int l31  = lane & 31;
  const int l5   = lane >> 5;

  const int wgid  = (int)blockIdx.x;
  const int split = wgid & 7;          // xcd-resident codebook slab
  const int mtile = wgid >> 3;
  const int rbase = mtile * ZTILE;
  const int cbase = split * COLS_PER_SPLIT;

  int cA[2], zA[2];
#pragma unroll
  for (int mi = 0; mi < 2; ++mi) {
    const int r = wc * 64 + mi * 32 + l31;
    cA[mi] = r * 64 + (((2 * l5) ^ ((r >> 1) & 3)) << 4);
  }
#pragma unroll
  for (int nj = 0; nj < 2; ++nj) {
    const int r = wz * 64 + nj * 32 + l31;
    zA[nj] = r * 64 + (((2 * l5) ^ ((r >> 1) & 3)) << 4);
  }

  const long stoff = (long)(tid >> 2) * D_DIM + (((tid & 3) ^ ((tid >> 3) & 3)) << 4);
  const unsigned char* zsp = zf8 + (size_t)rbase * D_DIM + stoff;
  const unsigned char* csp = cbf8 + (size_t)cbase * D_DIM + stoff;

  f32x16 acc[2][2];
#pragma unroll
  for (int mi = 0; mi < 2; ++mi)
#pragma unroll
    for (int nj = 0; nj < 2; ++nj)
#pragma unroll
      for (int r = 0; r < 16; ++r) acc[mi][nj][r] = 0.f;

  unsigned tk[2][8];                 // sorted ascending; tk[0] = min; pure u32
#pragma unroll
  for (int l = 0; l < 2; ++l)
#pragma unroll
    for (int q = 0; q < 8; ++q) tk[l][q] = 0u;

  auto STAGE = [&](int par) {
    unsigned char* zd = smem + par * 8192 + tid * 16;
    unsigned char* cd = smem + 16384 + par * 8192 + tid * 16;
    gload_lds16(zsp,               zd);
    gload_lds16(zsp + 64 * D_DIM,  zd + 4096);
    gload_lds16(csp,               cd);
    gload_lds16(csp + 64 * D_DIM,  cd + 4096);
  };
  auto ADV = [&](int stagedBody) {
    if (((stagedBody + 1) & 15) == 0) {
      zsp += 64 - D_DIM;                       // Z k-tiles repeat each chunk
      csp += 64 + (CTILE * D_DIM - D_DIM);     // C -> next 128-entry slab
    } else {
      zsp += 64; csp += 64;
    }
  };
  auto COMPUTE = [&](int par) {
    const unsigned char* Z = smem + par * 8192;
    const unsigned char* C = smem + 16384 + par * 8192;
    int8v cf[2], zr[2];
#pragma unroll
    for (int mi = 0; mi < 2; ++mi) {
      ((int4v*)&cf[mi])[0] = *(const int4v*)(C + cA[mi]);
      ((int4v*)&cf[mi])[1] = *(const int4v*)(C + (cA[mi] ^ 16));
    }
#pragma unroll
    for (int nj = 0; nj < 2; ++nj) {
      ((int4v*)&zr[nj])[0] = *(const int4v*)(Z + zA[nj]);
      ((int4v*)&zr[nj])[1] = *(const int4v*)(Z + (zA[nj] ^ 16));
    }
    __builtin_amdgcn_s_setprio(1);
#pragma unroll
    for (int mi = 0; mi < 2; ++mi)
#pragma unroll
      for (int nj = 0; nj < 2; ++nj)
        acc[mi][nj] = __builtin_amdgcn_mfma_scale_f32_32x32x64_f8f6f4(
            cf[mi], zr[nj], acc[mi][nj],
            0 /*A=fp8 e4m3*/, 0 /*B=fp8 e4m3*/, 0, 0x7F, 0, 0x7F);
    __builtin_amdgcn_s_setprio(0);
  };
  auto EPILOGUE = [&](int chunk) {
    const int cfb0 = cbase + chunk * CTILE + wc * 64 + l5 * 4;
#pragma unroll
    for (int nj = 0; nj < 2; ++nj) {
#pragma unroll
      for (int mi = 0; mi < 2; ++mi) {
#pragma unroll
        for (int r = 0; r < 16; ++r) {
          const float v = acc[mi][nj][r];
          const unsigned idx = (unsigned)(cfb0 + mi * 32 + (r & 3) + ((r >> 2) << 3));
          const unsigned key = (f2sortable(v) & ~0xFFFu) | idx;
          if (key > tk[nj][0]) {               // pure u32 gate; sorted insert
            unsigned cur = key;
#pragma unroll
            for (int q = 0; q < 7; ++q) {
              const unsigned a = tk[nj][q + 1];
              tk[nj][q] = (a < cur) ? a : cur;
              cur       = (a < cur) ? cur : a;
            }
            tk[nj][7] = cur;
          }
          acc[mi][nj][r] = 0.f;
        }
      }
    }
  };

  STAGE(0);
  ADV(0);
  __syncthreads();

  for (int b = 0; b < BODIES; b += 2) {
    STAGE(1);
    ADV(b + 1);
    COMPUTE(0);
    __syncthreads();

    if (b + 2 < BODIES) {
      STAGE(0);
      ADV(b + 2);
    }
    COMPUTE(1);
    if ((b & 15) == 14) EPILOGUE((b + 1) >> 4);   // chunks end at bodies 15/31/47/63
    __syncthreads();
  }

  unsigned* mrg = (unsigned*)smem;     // [128][33] u32 = 16.9 KB
  {
    const int slotw = (wc * 2 + l5) * 8;
#pragma unroll
    for (int nj = 0; nj < 2; ++nj) {
      const int zrow = wz * 64 + nj * 32 + l31;
#pragma unroll
      for (int q = 0; q < 8; ++q) mrg[zrow * 33 + slotw + q] = tk[nj][q];
    }
  }
  __syncthreads();
  if (tid < ZTILE) {
    const unsigned* c = mrg + tid * 33;
    unsigned top[8];
#pragma unroll
    for (int p = 0; p < 8; ++p) top[p] = 0u;
    unsigned tmin = 0u;
    for (int q0 = 0; q0 < 32; ++q0) {
      const unsigned k = c[(q0 + tid) & 31];
      if (k > tmin) {
        int ms = 0;
        unsigned mv = top[0];
#pragma unroll
        for (int q = 1; q < 8; ++q) { if (top[q] < mv) { mv = top[q]; ms = q; } }
#pragma unroll
        for (int q = 0; q < 8; ++q) top[q] = (q == ms) ? k : top[q];
        mv = top[0];
#pragma unroll
        for (int q = 1; q < 8; ++q) mv = (top[q] < mv) ? top[q] : mv;
        tmin = mv;
      }
    }
    unsigned* dst = part + ((size_t)(rbase + tid) * NS + split) * 8;
#pragma unroll
    for (int p = 0; p < 8; ++p) dst[p] = top[p];
  }
}

// ---------------- Kernel 3: wave-per-row merge + softmax + bf16-E gather + gate ----------------
// Lane l holds key l; top-8 via 8x wave-xor-max; per-lane softmax (8 expf).
// E gathered as bf16 (ushort8 = 16B/lane, half of R22's bytes); convert by
// <<16. Lane covers floats of chunks (lane+64i), i=0..1: 16 floats.
// Writes contiguous float4. SCALE = 10/256 (x16-scaled operands).
template<int EBF>
__global__ __launch_bounds__(256)
void k_gate(const unsigned* __restrict__ part, const float* __restrict__ target,
            const float* __restrict__ E, const unsigned short* __restrict__ Eb,
            float* __restrict__ out) {
  const int row  = blockIdx.x * 4 + (threadIdx.x >> 6);
  const int lane = threadIdx.x & 63;

  unsigned k = part[(size_t)row * 64 + lane];
  unsigned kp[8];
#pragma unroll
  for (int p = 0; p < 8; ++p) {
    unsigned m = k;
#pragma unroll
    for (int off = 32; off > 0; off >>= 1) {
      const unsigned o = __shfl_xor(m, off, 64);
      m = (m > o) ? m : o;
    }
    kp[p] = m;
    if (k == m) k = 0u;
  }

  const float SCALE = 10.0f / 256.0f;
  const float vmax = SCALE * sortable2f(kp[0] & ~0xFFFu);
  float a[8];
  float s = 0.f;
#pragma unroll
  for (int p = 0; p < 8; ++p) {
    a[p] = expf(SCALE * sortable2f(kp[p] & ~0xFFFu) - vmax);
    s += a[p];
  }
  const float inv = 1.0f / s;

  if (EBF) {
    float g[16];
#pragma unroll
    for (int e = 0; e < 16; ++e) g[e] = 0.f;
#pragma unroll
    for (int p = 0; p < 8; ++p) {
      const float ap = a[p] * inv;
      const unsigned short* ep = Eb + (size_t)(kp[p] & 0xFFFu) * D_DIM;
#pragma unroll
      for (int i = 0; i < 2; ++i) {
        const ushort8 e8 = *(const ushort8*)(ep + (lane + 64 * i) * 8);
#pragma unroll
        for (int e = 0; e < 8; ++e)
          g[8 * i + e] += ap * __uint_as_float(((unsigned)e8[e]) << 16);
      }
    }
    const float4* tg = (const float4*)(target + (size_t)row * D_DIM);
    float4* op = (float4*)(out + (size_t)row * D_DIM);
#pragma unroll
    for (int i = 0; i < 2; ++i)
#pragma unroll
      for (int j = 0; j < 2; ++j) {
        const int f4 = 2 * (lane + 64 * i) + j;
        const float4 t4 = tg[f4];
        float4 o;
        o.x = t4.x * (1.f + g[8 * i + 4 * j + 0]);
        o.y = t4.y * (1.f + g[8 * i + 4 * j + 1]);
        o.z = t4.z * (1.f + g[8 * i + 4 * j + 2]);
        o.w = t4.w * (1.f + g[8 * i + 4 * j + 3]);
        op[f4] = o;
      }
  } else {
    float4 g[4];
#pragma unroll
    for (int i = 0; i < 4; ++i) g[i] = (float4){0.f, 0.f, 0.f, 0.f};
#pragma unroll
    for (int p = 0; p < 8; ++p) {
      const float ap = a[p] * inv;
      const float4* ep = (const float4*)(E + (size_t)(kp[p] & 0xFFFu) * D_DIM);
#pragma unroll
      for (int i = 0; i < 4; ++i) {
        const float4 e4 = ep[lane + 64 * i];
        g[i].x += ap * e4.x;
        g[i].y += ap * e4.y;
        g[i].z += ap * e4.z;
        g[i].w += ap * e4.w;
      }
    }
    const float4* tg = (const float4*)(target + (size_t)row * D_DIM);
    float4* op = (float4*)(out + (size_t)row * D_DIM);
#pragma unroll
    for (int i = 0; i < 4; ++i) {
      const float4 t4 = tg[lane + 64 * i];
      float4 o;
      o.x = t4.x * (1.f + g[i].x);
      o.y = t4.y * (1.f + g[i].y);
      o.z = t4.z * (1.f + g[i].z);
      o.w = t4.w * (1.f + g[i].w);
      op[lane + 64 * i] = o;
    }
  }
}

extern "C" void kernel_launch(void* const* d_in, const int* in_sizes, int n_in,
                              void* d_out, int out_size, void* d_ws, size_t ws_size,
                              hipStream_t stream) {
  const float* z      = (const float*)d_in[0];
  const float* target = (const float*)d_in[1];
  const float* cb     = (const float*)d_in[2];
  const float* E      = (const float*)d_in[3];
  float* out = (float*)d_out;

  // d_out doubles as scratch for the fp8 normalized matrices (dead before k_gate writes)
  unsigned char* zf8  = (unsigned char*)d_out;                        // 16 MB
  unsigned char* cbf8 = (unsigned char*)d_out + 16777216;             // 4 MB @ +16MB
  unsigned* part = (unsigned*)d_ws;                                   // 4 MB
  unsigned short* Eb = (unsigned short*)((char*)d_ws + 4194304);      // 8 MB @ +4MB

  const bool ebf = (ws_size >= (size_t)(4194304 + 8388608));

  k_normalize<<<dim3((M_ROWS + K_CB) / 4), dim3(256), 0, stream>>>(z, cb, zf8, cbf8);
  if (ebf)
    k_e2bf<<<dim3(K_CB * D_DIM / (256 * 8)), dim3(256), 0, stream>>>(E, Eb);
  k_gemm_topk<<<dim3(MBLOCKS * NS), dim3(256), 0, stream>>>(zf8, cbf8, part);
  if (ebf)
    k_gate<1><<<dim3(M_ROWS / 4), dim3(256), 0, stream>>>(part, target, E, Eb, out);
  else
    k_gate<0><<<dim3(M_ROWS / 4), dim3(256), 0, stream>>>(part, target, E, Eb, out);
}